// Round 4
// baseline (591.758 us; speedup 1.0000x reference)
//
#include <hip/hip_runtime.h>

typedef unsigned short u16;
typedef __attribute__((ext_vector_type(8))) short bf16x8;
typedef __attribute__((ext_vector_type(8))) u16  u16x8;
typedef __attribute__((ext_vector_type(4))) float f32x4;

#define TOK   33048      // B*J*N = 8*17*243
#define NSEQ  243
#define ROWQ  1536       // ws3 row width (Q|K|V for current phase)

__device__ __forceinline__ float bf2f(u16 u){
    union { unsigned int i; float f; } v; v.i = ((unsigned int)u) << 16; return v.f;
}
__device__ __forceinline__ u16 f2bf(float f){
    union { float f; unsigned int i; } v; v.f = f;
    unsigned int r = v.i + 0x7fffu + ((v.i >> 16) & 1u);
    return (u16)(r >> 16);
}

__device__ __forceinline__ void gload_lds16(const void* g, void* l){
    __builtin_amdgcn_global_load_lds(
        (const __attribute__((address_space(1))) unsigned int*)g,
        (__attribute__((address_space(3))) unsigned int*)l, 16, 0, 0);
}

// ---------------- x -> token-major bf16 ----------------
__global__ __launch_bounds__(256) void k_cvt_xbf(const float* __restrict__ x, u16* __restrict__ xbf){
    int idx = blockIdx.x*256 + threadIdx.x;   // 33048*64 = 2,115,072
    int t  = idx >> 6;
    int c8 = (idx & 63) << 3;
    unsigned b   = (unsigned)t / 4131u;
    unsigned rem = (unsigned)t % 4131u;
    unsigned j = rem / 243u, n = rem % 243u;
    const float* src = x + ((size_t)(b*243u + n)*17u + j)*512u + c8;
    f32x4 a = *(const f32x4*)src;
    f32x4 c = *(const f32x4*)(src+4);
    u16x8 o;
    #pragma unroll
    for (int e=0;e<4;e++){ o[e]=f2bf(a[e]); o[e+4]=f2bf(c[e]); }
    *(u16x8*)(xbf + (size_t)t*512 + c8) = o;
}

// ---------------- weight conversions ----------------
__global__ __launch_bounds__(256) void k_cvt_wcat(const float* __restrict__ Wqkv,
                                                  const float* __restrict__ Wq,
                                                  const float* __restrict__ Wkv,
                                                  u16* __restrict__ WcatT){
    int idx = blockIdx.x*256 + threadIdx.x;   // 196608 total
    int k  = idx / 384;
    int c0 = (idx % 384) * 8;
    const float* src;
    if (c0 < 1536)      src = Wqkv + (size_t)k*1536 + c0;
    else if (c0 < 2048) src = Wq   + (size_t)k*512  + (c0 - 1536);
    else                src = Wkv  + (size_t)k*1024 + (c0 - 2048);
    f32x4 a = *(const f32x4*)src;
    f32x4 b = *(const f32x4*)(src+4);
    #pragma unroll
    for (int e=0;e<4;e++){
        WcatT[(size_t)(c0+e)*512 + k]   = f2bf(a[e]);
        WcatT[(size_t)(c0+4+e)*512 + k] = f2bf(b[e]);
    }
}

__global__ __launch_bounds__(256) void k_cvt_wproj(const float* __restrict__ Wp, u16* __restrict__ WpT){
    int idx = blockIdx.x*256 + threadIdx.x;   // 32768 total
    int k  = idx / 64;
    int c0 = (idx % 64) * 8;
    f32x4 a = *(const f32x4*)(Wp + (size_t)k*512 + c0);
    f32x4 b = *(const f32x4*)(Wp + (size_t)k*512 + c0 + 4);
    #pragma unroll
    for (int e=0;e<4;e++){
        WpT[(size_t)(c0+e)*512 + k]   = f2bf(a[e]);
        WpT[(size_t)(c0+4+e)*512 + k] = f2bf(b[e]);
    }
}

// ---------------- input GEMM  M=33048 x N=1536(half) x K=512 ----------------
// writes ws3[t][1536]: cols 0..511 = Q, 512..1023 = K, 1024..1535 = V
__global__ __launch_bounds__(256) void k_gemm_in(
    const u16* __restrict__ xbf, const u16* __restrict__ WcatT,
    const float* __restrict__ b_qkv, const float* __restrict__ b_q,
    const float* __restrict__ b_kv, u16* __restrict__ ws3, int c_off)
{
    __shared__ __align__(16) u16 smem[8192];   // 16KB; As=[128][32], Bs=[128][32]
    u16* As = smem;
    u16* Bs = smem + 4096;

    // bijective XCD swizzle over 3108 blocks (q=388, r=4)
    const int orig = blockIdx.x;
    const int xcd  = orig & 7;
    const int wg   = (xcd < 4 ? xcd*389 : 4*389 + (xcd-4)*388) + (orig >> 3);
    const int nt = wg % 12, mt = wg / 12;

    const int tid = threadIdx.x;
    const int w = tid >> 6, lane = tid & 63;
    const int wm = w >> 1, wn = w & 1;
    const int lg = lane >> 4, li = lane & 15;

    // staging mapping: wave w load0 -> rows [w*16, w*16+16), load1 -> +64
    const int srow = w*16 + (lane >> 2);
    const int scol = (lane & 3) * 8;
    const u16* gA0 = xbf   + (size_t)(mt*128 + srow)*512 + scol;
    const u16* gA1 = gA0 + (size_t)64*512;
    const u16* gB0 = WcatT + (size_t)(c_off + nt*128 + srow)*512 + scol;
    const u16* gB1 = gB0 + (size_t)64*512;
    u16* lA0 = As + w*512;           u16* lA1 = As + 2048 + w*512;
    u16* lB0 = Bs + w*512;           u16* lB1 = Bs + 2048 + w*512;

    f32x4 acc[4][4];
    #pragma unroll
    for (int i=0;i<4;i++)
        #pragma unroll
        for (int jj=0;jj<4;jj++){ acc[i][jj][0]=0.f; acc[i][jj][1]=0.f; acc[i][jj][2]=0.f; acc[i][jj][3]=0.f; }

    for (int k0 = 0; k0 < 512; k0 += 32){
        __syncthreads();
        gload_lds16(gA0 + k0, lA0);
        gload_lds16(gA1 + k0, lA1);
        gload_lds16(gB0 + k0, lB0);
        gload_lds16(gB1 + k0, lB1);
        __syncthreads();
        bf16x8 av[4], bv[4];
        #pragma unroll
        for (int mf=0;mf<4;mf++) av[mf] = *(const bf16x8*)&As[(wm*64 + mf*16 + li)*32 + lg*8];
        #pragma unroll
        for (int nf=0;nf<4;nf++) bv[nf] = *(const bf16x8*)&Bs[(wn*64 + nf*16 + li)*32 + lg*8];
        #pragma unroll
        for (int mf=0;mf<4;mf++)
            #pragma unroll
            for (int nf=0;nf<4;nf++)
                acc[mf][nf] = __builtin_amdgcn_mfma_f32_16x16x32_bf16(av[mf], bv[nf], acc[mf][nf], 0, 0, 0);
    }

    // bias per output column (this thread's li column of each nf)
    float bias[4];
    #pragma unroll
    for (int nf=0;nf<4;nf++){
        const int c = c_off + nt*128 + wn*64 + nf*16 + li;
        bias[nf] = (c < 1536) ? b_qkv[c] : (c < 2048 ? b_q[c-1536] : b_kv[c-2048]);
    }

    // epilogue: per-wave 16x72 LDS transpose -> 16B stores
    u16* L = smem + w*1152;          // 16 rows x 72 u16 (byte stride 144, 16B-aligned)
    const int colbase = nt*128 + wn*64;
    const int rloc = lane & 15;
    const int cchunk = lane >> 4;
    #pragma unroll
    for (int mf=0;mf<4;mf++){
        __syncthreads();
        #pragma unroll
        for (int nf=0;nf<4;nf++)
            #pragma unroll
            for (int reg=0;reg<4;reg++)
                L[(lg*4+reg)*72 + nf*16 + li] = f2bf(acc[mf][nf][reg] + bias[nf]);
        __syncthreads();
        const int rr = mt*128 + wm*64 + mf*16 + rloc;
        if (rr < TOK){
            u16x8 v0 = *(const u16x8*)&L[rloc*72 + cchunk*8];
            u16x8 v1 = *(const u16x8*)&L[rloc*72 + 32 + cchunk*8];
            u16* dst = ws3 + (size_t)rr*ROWQ + colbase + cchunk*8;
            *(u16x8*)dst      = v0;
            *(u16x8*)(dst+32) = v1;
        }
    }
}

// ---------------- fused attention per (b,j,h) group, one phase per launch ----------------
// LDS: Vs (33.8KB) + Ps (33.8KB) = 67.6KB -> 2 blocks/CU. K fragments read from L2.
__constant__ int g_child[17][3] = {
  {1,4,7},{2,-1,-1},{3,-1,-1},{3,-1,-1},{5,-1,-1},{6,-1,-1},{6,-1,-1},{8,-1,-1},
  {9,11,14},{10,-1,-1},{10,-1,-1},{12,-1,-1},{13,-1,-1},{13,-1,-1},{15,-1,-1},
  {16,-1,-1},{16,-1,-1}};
__constant__ float g_cw[17] = {0.33333333f,1,1,1,1,1,1,1,0.33333333f,1,1,1,1,1,1,1,1};

__global__ __launch_bounds__(256) void k_attn(const u16* __restrict__ ws3, u16* __restrict__ attn, int phase)
{
    __shared__ __align__(16) u16 Vs[64][264];     // V transposed [d][n], padded
    __shared__ __align__(16) u16 Ps[4][16][264];  // per-wave P (no cross-wave use)

    const int g = blockIdx.x;              // = bj*8 + h
    const int bj = g >> 3, h = g & 7;
    const int b_ = bj / 17, j_ = bj % 17;

    const int tid = threadIdx.x, lane = tid & 63, w = tid >> 6;
    const int lg = lane >> 4, li = lane & 15;

    const int srow  = tid >> 2;
    const int spart = (tid & 3) * 16;

    // ---- stage V (transposed); phase 1 applies child-mean mix ----
    for (int sw = 0; sw < 4; sw++){
        const int row = sw*64 + srow;
        u16x8 vA = {0,0,0,0,0,0,0,0}, vB = vA;
        if (row < NSEQ){
            if (phase == 0){
                const u16* vp = ws3 + (size_t)(bj*243 + row)*ROWQ + 1024 + h*64 + spart;
                vA = *(const u16x8*)vp;  vB = *(const u16x8*)(vp+8);
            } else {
                float va[16];
                #pragma unroll
                for (int e=0;e<16;e++) va[e]=0.f;
                const float wgt = g_cw[j_];
                #pragma unroll
                for (int ci=0; ci<3; ci++){
                    const int cj = g_child[j_][ci];
                    if (cj >= 0){
                        const u16* vp = ws3 + (size_t)((b_*17+cj)*243 + row)*ROWQ + 1024 + h*64 + spart;
                        const u16x8 c0 = *(const u16x8*)vp, c1 = *(const u16x8*)(vp+8);
                        #pragma unroll
                        for (int e=0;e<8;e++){
                            va[e]   += wgt*bf2f(c0[e]);
                            va[e+8] += wgt*bf2f(c1[e]);
                        }
                    }
                }
                #pragma unroll
                for (int e=0;e<8;e++){ vA[e]=f2bf(va[e]); vB[e]=f2bf(va[e+8]); }
            }
        }
        #pragma unroll
        for (int e=0;e<8;e++){
            Vs[spart+e][row]   = vA[e];
            Vs[spart+8+e][row] = vB[e];
        }
    }
    __syncthreads();

    const u16* Qg = ws3 + (size_t)(bj*243)*ROWQ + h*64;
    // softmax scale; phase 1 folds the child-mean weight of K into the scale
    const float scale = (phase == 0) ? 0.125f : 0.125f * g_cw[j_];

    for (int p = 0; p < 4; p++){
        const int qrow0 = p*64 + w*16;
        bf16x8 q0 = {0,0,0,0,0,0,0,0}, q1 = q0;
        const int qr = qrow0 + li;
        if (qr < NSEQ){
            q0 = *(const bf16x8*)(Qg + (size_t)qr*ROWQ + lg*8);
            q1 = *(const bf16x8*)(Qg + (size_t)qr*ROWQ + 32 + lg*8);
        }
        // S = Q K^T; K fragments straight from global (L1/L2-resident).
        // phase 1: S = sum over children of Q K_c^T (weight folded into scale)
        f32x4 sf[16];
        #pragma unroll
        for (int nt2=0; nt2<16; nt2++){
            f32x4 s; s[0]=0.f; s[1]=0.f; s[2]=0.f; s[3]=0.f;
            if (phase == 0){
                const u16* kp = ws3 + (size_t)(bj*243 + nt2*16+li)*ROWQ + 512 + h*64;
                const bf16x8 kb0 = *(const bf16x8*)(kp + lg*8);
                const bf16x8 kb1 = *(const bf16x8*)(kp + 32 + lg*8);
                s = __builtin_amdgcn_mfma_f32_16x16x32_bf16(q0, kb0, s, 0,0,0);
                s = __builtin_amdgcn_mfma_f32_16x16x32_bf16(q1, kb1, s, 0,0,0);
            } else {
                #pragma unroll
                for (int ci=0; ci<3; ci++){
                    const int cj = g_child[j_][ci];
                    if (cj >= 0){
                        const u16* kp = ws3 + (size_t)((b_*17+cj)*243 + nt2*16+li)*ROWQ + 512 + h*64;
                        const bf16x8 kb0 = *(const bf16x8*)(kp + lg*8);
                        const bf16x8 kb1 = *(const bf16x8*)(kp + 32 + lg*8);
                        s = __builtin_amdgcn_mfma_f32_16x16x32_bf16(q0, kb0, s, 0,0,0);
                        s = __builtin_amdgcn_mfma_f32_16x16x32_bf16(q1, kb1, s, 0,0,0);
                    }
                }
            }
            sf[nt2] = s;
        }
        if (li >= 3){ sf[15][0]=-1e30f; sf[15][1]=-1e30f; sf[15][2]=-1e30f; sf[15][3]=-1e30f; }
        // softmax per q-row (row = lg*4+r; cols across li lanes)
        #pragma unroll
        for (int r=0;r<4;r++){
            float m = sf[0][r];
            #pragma unroll
            for (int nt2=1;nt2<16;nt2++) m = fmaxf(m, sf[nt2][r]);
            m = fmaxf(m, __shfl_xor(m,1));
            m = fmaxf(m, __shfl_xor(m,2));
            m = fmaxf(m, __shfl_xor(m,4));
            m = fmaxf(m, __shfl_xor(m,8));
            float sum = 0.f;
            #pragma unroll
            for (int nt2=0;nt2<16;nt2++){
                const float pv = __expf(scale*(sf[nt2][r]-m));
                sf[nt2][r] = pv; sum += pv;
            }
            sum += __shfl_xor(sum,1);
            sum += __shfl_xor(sum,2);
            sum += __shfl_xor(sum,4);
            sum += __shfl_xor(sum,8);
            const float inv = 1.f/sum;
            #pragma unroll
            for (int nt2=0;nt2<16;nt2++)
                Ps[w][lg*4+r][nt2*16+li] = f2bf(sf[nt2][r]*inv);
        }
        // Ps is per-wave: no __syncthreads needed. Keep compiler from reordering.
        asm volatile("" ::: "memory");
        // O = P V
        bf16x8 pa[8];
        #pragma unroll
        for (int kt=0;kt<8;kt++) pa[kt] = *(const bf16x8*)&Ps[w][li][kt*32 + lg*8];
        f32x4 ov[4];
        #pragma unroll
        for (int dn=0;dn<4;dn++){
            f32x4 o; o[0]=0.f; o[1]=0.f; o[2]=0.f; o[3]=0.f;
            #pragma unroll
            for (int kt=0;kt<8;kt++){
                const bf16x8 vb = *(const bf16x8*)&Vs[dn*16+li][kt*32 + lg*8];
                o = __builtin_amdgcn_mfma_f32_16x16x32_bf16(pa[kt], vb, o, 0,0,0);
            }
            ov[dn] = o;
        }
        #pragma unroll
        for (int dn=0;dn<4;dn++){
            #pragma unroll
            for (int reg=0;reg<4;reg++){
                const int qrow = qrow0 + lg*4 + reg;
                if (qrow < NSEQ){
                    const size_t off = ((size_t)bj*243 + qrow)*512 + h*64 + dn*16 + li;
                    float val = ov[dn][reg];
                    if (phase == 1) val += bf2f(attn[off]);
                    attn[off] = f2bf(val);
                }
            }
        }
        asm volatile("" ::: "memory");
    }
}

// ---------------- projection GEMM  M=33048 x N=512 x K=512 -> fp32 fuse ----------------
__global__ __launch_bounds__(256) void k_gemm_proj(
    const u16* __restrict__ attnb, const u16* __restrict__ WprojT,
    const float* __restrict__ b_proj, float* __restrict__ fuse)
{
    __shared__ __align__(16) u16 smem[8192];
    u16* As = smem;
    u16* Bs = smem + 4096;

    // bijective XCD swizzle over 1036 blocks (q=129, r=4)
    const int orig = blockIdx.x;
    const int xcd  = orig & 7;
    const int wg   = (xcd < 4 ? xcd*130 : 4*130 + (xcd-4)*129) + (orig >> 3);
    const int nt = wg & 3, mt = wg >> 2;

    const int tid = threadIdx.x;
    const int w = tid >> 6, lane = tid & 63;
    const int wm = w >> 1, wn = w & 1;
    const int lg = lane >> 4, li = lane & 15;

    const int srow = w*16 + (lane >> 2);
    const int scol = (lane & 3) * 8;
    const u16* gA0 = attnb  + (size_t)(mt*128 + srow)*512 + scol;
    const u16* gA1 = gA0 + (size_t)64*512;
    const u16* gB0 = WprojT + (size_t)(nt*128 + srow)*512 + scol;
    const u16* gB1 = gB0 + (size_t)64*512;
    u16* lA0 = As + w*512;           u16* lA1 = As + 2048 + w*512;
    u16* lB0 = Bs + w*512;           u16* lB1 = Bs + 2048 + w*512;

    f32x4 acc[4][4];
    #pragma unroll
    for (int i=0;i<4;i++)
        #pragma unroll
        for (int jj=0;jj<4;jj++){ acc[i][jj][0]=0.f; acc[i][jj][1]=0.f; acc[i][jj][2]=0.f; acc[i][jj][3]=0.f; }

    for (int k0 = 0; k0 < 512; k0 += 32){
        __syncthreads();
        gload_lds16(gA0 + k0, lA0);
        gload_lds16(gA1 + k0, lA1);
        gload_lds16(gB0 + k0, lB0);
        gload_lds16(gB1 + k0, lB1);
        __syncthreads();
        bf16x8 av[4], bv[4];
        #pragma unroll
        for (int mf=0;mf<4;mf++) av[mf] = *(const bf16x8*)&As[(wm*64 + mf*16 + li)*32 + lg*8];
        #pragma unroll
        for (int nf=0;nf<4;nf++) bv[nf] = *(const bf16x8*)&Bs[(wn*64 + nf*16 + li)*32 + lg*8];
        #pragma unroll
        for (int mf=0;mf<4;mf++)
            #pragma unroll
            for (int nf=0;nf<4;nf++)
                acc[mf][nf] = __builtin_amdgcn_mfma_f32_16x16x32_bf16(av[mf], bv[nf], acc[mf][nf], 0, 0, 0);
    }

    #pragma unroll
    for (int mf=0;mf<4;mf++)
        #pragma unroll
        for (int reg=0;reg<4;reg++){
            const int rr = mt*128 + wm*64 + mf*16 + lg*4 + reg;
            if (rr < TOK){
                #pragma unroll
                for (int nf=0;nf<4;nf++){
                    const int c = nt*128 + wn*64 + nf*16 + li;
                    fuse[(size_t)rr*512 + c] = acc[mf][nf][reg] + b_proj[c];
                }
            }
        }
}

// ---------------- residual + LayerNorm (with (b,j,n)->(b,n,j) permute) ----------------
__global__ __launch_bounds__(256) void k_ln(
    const float* __restrict__ x, const float* __restrict__ fuse, float* __restrict__ out)
{
    const int w = threadIdx.x >> 6, lane = threadIdx.x & 63;
    const int o = blockIdx.x*4 + w;     // row in (b,n,j) order, exact 33048
    const unsigned b_  = (unsigned)o / 4131u;
    const unsigned rem = (unsigned)o % 4131u;
    const unsigned n = rem / 17u, j = rem % 17u;
    const unsigned t = (b_*17u + j)*243u + n;
    const float* fr = fuse + (size_t)t*512 + lane*8;
    const float* xr = x    + (size_t)o*512 + lane*8;
    f32x4 f0 = *(const f32x4*)fr, f1 = *(const f32x4*)(fr+4);
    f32x4 x0 = *(const f32x4*)xr, x1 = *(const f32x4*)(xr+4);
    float y[8];
    #pragma unroll
    for (int e=0;e<4;e++){ y[e] = x0[e]+f0[e]; y[e+4] = x1[e]+f1[e]; }
    float s1=0.f, s2=0.f;
    #pragma unroll
    for (int e=0;e<8;e++){ s1 += y[e]; s2 += y[e]*y[e]; }
    #pragma unroll
    for (int m=1;m<64;m<<=1){ s1 += __shfl_xor(s1,m); s2 += __shfl_xor(s2,m); }
    const float mu  = s1 * (1.f/512.f);
    const float var = s2 * (1.f/512.f) - mu*mu;
    const float rstd = rsqrtf(var + 1e-5f);
    float* orow = out + (size_t)o*512 + lane*8;
    f32x4 o0, o1;
    #pragma unroll
    for (int e=0;e<4;e++){ o0[e] = (y[e]-mu)*rstd; o1[e] = (y[e+4]-mu)*rstd; }
    *(f32x4*)orow = o0; *(f32x4*)(orow+4) = o1;
}

extern "C" void kernel_launch(void* const* d_in, const int* in_sizes, int n_in,
                              void* d_out, int out_size, void* d_ws, size_t ws_size,
                              hipStream_t stream)
{
    const float* x      = (const float*)d_in[0];
    const float* W_qkv  = (const float*)d_in[1];
    const float* b_qkv  = (const float*)d_in[2];
    const float* W_q    = (const float*)d_in[3];
    const float* b_q    = (const float*)d_in[4];
    const float* W_kv   = (const float*)d_in[5];
    const float* b_kv   = (const float*)d_in[6];
    const float* W_proj = (const float*)d_in[7];
    const float* b_proj = (const float*)d_in[8];

    // workspace layout (peak ~173.1 MB):
    //   [0, 33972224)                       xbf  bf16 [33048+128 pad][512]
    //   [33972224, 135495680)               ws3  bf16 [33048][1536]  (Q|K|V of current phase)
    //   [135495680, 169467904)              attn bf16 [33048+128 pad][512]
    //   [169467904, 172613632)              WcatT bf16 [3072][512]
    //   [172613632, 173137920)              WprojT bf16 [512][512]
    //   fuse (fp32, 67.7MB) aliases ws3 (dead after attn phase 1)
    char* ws = (char*)d_ws;
    u16*   xbf    = (u16*)(ws);
    u16*   ws3    = (u16*)(ws + 33972224u);
    u16*   attn   = (u16*)(ws + 135495680u);
    u16*   WcatT  = (u16*)(ws + 169467904u);
    u16*   WprojT = (u16*)(ws + 172613632u);
    float* fuse   = (float*)(ws + 33972224u);
    float* out    = (float*)d_out;

    k_cvt_xbf  <<<8262, 256, 0, stream>>>(x, xbf);
    k_cvt_wcat <<<768,  256, 0, stream>>>(W_qkv, W_q, W_kv, WcatT);
    k_cvt_wproj<<<128,  256, 0, stream>>>(W_proj, WprojT);

    k_gemm_in<<<3108, 256, 0, stream>>>(xbf, WcatT, b_qkv, b_q, b_kv, ws3, 0);
    k_attn<<<1088, 256, 0, stream>>>(ws3, attn, 0);

    k_gemm_in<<<3108, 256, 0, stream>>>(xbf, WcatT, b_qkv, b_q, b_kv, ws3, 1536);
    k_attn<<<1088, 256, 0, stream>>>(ws3, attn, 1);

    k_gemm_proj<<<1036, 256, 0, stream>>>(attn, WprojT, b_proj, fuse);

    k_ln<<<8262, 256, 0, stream>>>(x, fuse, out);
}

// Round 5
// 489.216 us; speedup vs baseline: 1.2096x; 1.2096x over previous
//
#include <hip/hip_runtime.h>

typedef unsigned short u16;
typedef unsigned int u32;
typedef __attribute__((ext_vector_type(8))) short bf16x8;
typedef __attribute__((ext_vector_type(8))) u16  u16x8;
typedef __attribute__((ext_vector_type(4))) float f32x4;

#define TOK   33048      // B*J*N = 8*17*243
#define NSEQ  243
#define ROWQ  1536       // ws3 row width (Q|K|V for current phase)

__device__ __forceinline__ float bf2f(u16 u){
    union { unsigned int i; float f; } v; v.i = ((unsigned int)u) << 16; return v.f;
}
__device__ __forceinline__ u16 f2bf(float f){
    union { float f; unsigned int i; } v; v.f = f;
    unsigned int r = v.i + 0x7fffu + ((v.i >> 16) & 1u);
    return (u16)(r >> 16);
}

__device__ __forceinline__ void gload_lds16(const void* g, void* l){
    __builtin_amdgcn_global_load_lds(
        (const __attribute__((address_space(1))) unsigned int*)g,
        (__attribute__((address_space(3))) unsigned int*)l, 16, 0, 0);
}

// ---------------- x -> token-major bf16 ----------------
__global__ __launch_bounds__(256) void k_cvt_xbf(const float* __restrict__ x, u16* __restrict__ xbf){
    int idx = blockIdx.x*256 + threadIdx.x;   // 33048*64 = 2,115,072
    int t  = idx >> 6;
    int c8 = (idx & 63) << 3;
    unsigned b   = (unsigned)t / 4131u;
    unsigned rem = (unsigned)t % 4131u;
    unsigned j = rem / 243u, n = rem % 243u;
    const float* src = x + ((size_t)(b*243u + n)*17u + j)*512u + c8;
    f32x4 a = *(const f32x4*)src;
    f32x4 c = *(const f32x4*)(src+4);
    u16x8 o;
    #pragma unroll
    for (int e=0;e<4;e++){ o[e]=f2bf(a[e]); o[e+4]=f2bf(c[e]); }
    *(u16x8*)(xbf + (size_t)t*512 + c8) = o;
}

// ---------------- weight conversions ----------------
__global__ __launch_bounds__(256) void k_cvt_wcat(const float* __restrict__ Wqkv,
                                                  const float* __restrict__ Wq,
                                                  const float* __restrict__ Wkv,
                                                  u16* __restrict__ WcatT){
    int idx = blockIdx.x*256 + threadIdx.x;   // 196608 total
    int k  = idx / 384;
    int c0 = (idx % 384) * 8;
    const float* src;
    if (c0 < 1536)      src = Wqkv + (size_t)k*1536 + c0;
    else if (c0 < 2048) src = Wq   + (size_t)k*512  + (c0 - 1536);
    else                src = Wkv  + (size_t)k*1024 + (c0 - 2048);
    f32x4 a = *(const f32x4*)src;
    f32x4 b = *(const f32x4*)(src+4);
    #pragma unroll
    for (int e=0;e<4;e++){
        WcatT[(size_t)(c0+e)*512 + k]   = f2bf(a[e]);
        WcatT[(size_t)(c0+4+e)*512 + k] = f2bf(b[e]);
    }
}

__global__ __launch_bounds__(256) void k_cvt_wproj(const float* __restrict__ Wp, u16* __restrict__ WpT){
    int idx = blockIdx.x*256 + threadIdx.x;   // 32768 total
    int k  = idx / 64;
    int c0 = (idx % 64) * 8;
    f32x4 a = *(const f32x4*)(Wp + (size_t)k*512 + c0);
    f32x4 b = *(const f32x4*)(Wp + (size_t)k*512 + c0 + 4);
    #pragma unroll
    for (int e=0;e<4;e++){
        WpT[(size_t)(c0+e)*512 + k]   = f2bf(a[e]);
        WpT[(size_t)(c0+4+e)*512 + k] = f2bf(b[e]);
    }
}

// ---------------- input GEMM  M=33048 x N=1536(half) x K=512 ----------------
__global__ __launch_bounds__(256) void k_gemm_in(
    const u16* __restrict__ xbf, const u16* __restrict__ WcatT,
    const float* __restrict__ b_qkv, const float* __restrict__ b_q,
    const float* __restrict__ b_kv, u16* __restrict__ ws3, int c_off)
{
    __shared__ __align__(16) u16 smem[8192];   // 16KB; As=[128][32], Bs=[128][32]
    u16* As = smem;
    u16* Bs = smem + 4096;

    // bijective XCD swizzle over 3108 blocks (q=388, r=4)
    const int orig = blockIdx.x;
    const int xcd  = orig & 7;
    const int wg   = (xcd < 4 ? xcd*389 : 4*389 + (xcd-4)*388) + (orig >> 3);
    const int nt = wg % 12, mt = wg / 12;

    const int tid = threadIdx.x;
    const int w = tid >> 6, lane = tid & 63;
    const int wm = w >> 1, wn = w & 1;
    const int lg = lane >> 4, li = lane & 15;

    const int srow = w*16 + (lane >> 2);
    const int scol = (lane & 3) * 8;
    const u16* gA0 = xbf   + (size_t)(mt*128 + srow)*512 + scol;
    const u16* gA1 = gA0 + (size_t)64*512;
    const u16* gB0 = WcatT + (size_t)(c_off + nt*128 + srow)*512 + scol;
    const u16* gB1 = gB0 + (size_t)64*512;
    u16* lA0 = As + w*512;           u16* lA1 = As + 2048 + w*512;
    u16* lB0 = Bs + w*512;           u16* lB1 = Bs + 2048 + w*512;

    f32x4 acc[4][4];
    #pragma unroll
    for (int i=0;i<4;i++)
        #pragma unroll
        for (int jj=0;jj<4;jj++){ acc[i][jj][0]=0.f; acc[i][jj][1]=0.f; acc[i][jj][2]=0.f; acc[i][jj][3]=0.f; }

    for (int k0 = 0; k0 < 512; k0 += 32){
        __syncthreads();
        gload_lds16(gA0 + k0, lA0);
        gload_lds16(gA1 + k0, lA1);
        gload_lds16(gB0 + k0, lB0);
        gload_lds16(gB1 + k0, lB1);
        __syncthreads();
        bf16x8 av[4], bv[4];
        #pragma unroll
        for (int mf=0;mf<4;mf++) av[mf] = *(const bf16x8*)&As[(wm*64 + mf*16 + li)*32 + lg*8];
        #pragma unroll
        for (int nf=0;nf<4;nf++) bv[nf] = *(const bf16x8*)&Bs[(wn*64 + nf*16 + li)*32 + lg*8];
        #pragma unroll
        for (int mf=0;mf<4;mf++)
            #pragma unroll
            for (int nf=0;nf<4;nf++)
                acc[mf][nf] = __builtin_amdgcn_mfma_f32_16x16x32_bf16(av[mf], bv[nf], acc[mf][nf], 0, 0, 0);
    }

    float bias[4];
    #pragma unroll
    for (int nf=0;nf<4;nf++){
        const int c = c_off + nt*128 + wn*64 + nf*16 + li;
        bias[nf] = (c < 1536) ? b_qkv[c] : (c < 2048 ? b_q[c-1536] : b_kv[c-2048]);
    }

    // epilogue: per-wave 16x72 LDS transpose -> 16B stores
    u16* L = smem + w*1152;
    const int colbase = nt*128 + wn*64;
    const int rloc = lane & 15;
    const int cchunk = lane >> 4;
    #pragma unroll
    for (int mf=0;mf<4;mf++){
        __syncthreads();
        #pragma unroll
        for (int nf=0;nf<4;nf++)
            #pragma unroll
            for (int reg=0;reg<4;reg++)
                L[(lg*4+reg)*72 + nf*16 + li] = f2bf(acc[mf][nf][reg] + bias[nf]);
        __syncthreads();
        const int rr = mt*128 + wm*64 + mf*16 + rloc;
        if (rr < TOK){
            u16x8 v0 = *(const u16x8*)&L[rloc*72 + cchunk*8];
            u16x8 v1 = *(const u16x8*)&L[rloc*72 + 32 + cchunk*8];
            u16* dst = ws3 + (size_t)rr*ROWQ + colbase + cchunk*8;
            *(u16x8*)dst      = v0;
            *(u16x8*)(dst+32) = v1;
        }
    }
}

// ---------------- fused attention per (b,j,h) group, one phase per launch ----------------
// Swapped QK^T: each lane owns one q-row; softmax per-lane; P redistributed by shuffles.
// LDS: Ks 36.9KB + Vs 33.8KB = 70.7KB -> 2 blocks/CU. No barriers in the p-loop.
__constant__ int g_child[17][3] = {
  {1,4,7},{2,-1,-1},{3,-1,-1},{3,-1,-1},{5,-1,-1},{6,-1,-1},{6,-1,-1},{8,-1,-1},
  {9,11,14},{10,-1,-1},{10,-1,-1},{12,-1,-1},{13,-1,-1},{13,-1,-1},{15,-1,-1},
  {16,-1,-1},{16,-1,-1}};
__constant__ float g_cw[17] = {0.33333333f,1,1,1,1,1,1,1,0.33333333f,1,1,1,1,1,1,1,1};

__global__ __launch_bounds__(256) void k_attn(const u16* __restrict__ ws3, u16* __restrict__ attn, int phase)
{
    __shared__ __align__(16) u16 Ks[256][72];     // K rows (feat 0..63), padded
    __shared__ __align__(16) u16 Vs[64][264];     // V transposed [d][n], padded

    const int g = blockIdx.x;              // = bj*8 + h
    const int bj = g >> 3, h = g & 7;
    const int b_ = bj / 17, j_ = bj % 17;

    const int tid = threadIdx.x, lane = tid & 63, w = tid >> 6;
    const int lg = lane >> 4, li = lane & 15;

    const int srow  = tid >> 2;
    const int spart = (tid & 3) * 16;

    // ---- stage K (row-major) + V (transposed); phase 1 applies child-mean mix ----
    for (int sw = 0; sw < 4; sw++){
        const int row = sw*64 + srow;
        u16x8 kA = {0,0,0,0,0,0,0,0}, kB = kA, vA = kA, vB = kA;
        if (row < NSEQ){
            if (phase == 0){
                const u16* kp = ws3 + (size_t)(bj*243 + row)*ROWQ + 512 + h*64 + spart;
                kA = *(const u16x8*)kp;       kB = *(const u16x8*)(kp+8);
                vA = *(const u16x8*)(kp+512); vB = *(const u16x8*)(kp+520);
            } else {
                float ka[16], va[16];
                #pragma unroll
                for (int e=0;e<16;e++){ ka[e]=0.f; va[e]=0.f; }
                const float wgt = g_cw[j_];
                #pragma unroll
                for (int ci=0; ci<3; ci++){
                    const int cj = g_child[j_][ci];
                    if (cj >= 0){
                        const u16* kp = ws3 + (size_t)((b_*17+cj)*243 + row)*ROWQ + 512 + h*64 + spart;
                        const u16x8 a0 = *(const u16x8*)kp,       a1 = *(const u16x8*)(kp+8);
                        const u16x8 c0 = *(const u16x8*)(kp+512), c1 = *(const u16x8*)(kp+520);
                        #pragma unroll
                        for (int e=0;e<8;e++){
                            ka[e]   += wgt*bf2f(a0[e]); ka[e+8] += wgt*bf2f(a1[e]);
                            va[e]   += wgt*bf2f(c0[e]); va[e+8] += wgt*bf2f(c1[e]);
                        }
                    }
                }
                #pragma unroll
                for (int e=0;e<8;e++){
                    kA[e]=f2bf(ka[e]); kB[e]=f2bf(ka[e+8]);
                    vA[e]=f2bf(va[e]); vB[e]=f2bf(va[e+8]);
                }
            }
        }
        *(u16x8*)&Ks[row][spart]   = kA;
        *(u16x8*)&Ks[row][spart+8] = kB;
        #pragma unroll
        for (int e=0;e<8;e++){
            Vs[spart+e][row]   = vA[e];
            Vs[spart+8+e][row] = vB[e];
        }
    }
    __syncthreads();

    const u16* Qg = ws3 + (size_t)(bj*243)*ROWQ + h*64;
    const float scale = 0.125f;
    const int laneA = li + 32*(lg & 1);
    const int laneB = laneA + 16;
    const bool sel = (lg >> 1) != 0;

    for (int p = 0; p < 4; p++){
        const int qrow0 = p*64 + w*16;
        bf16x8 q0 = {0,0,0,0,0,0,0,0}, q1 = q0;
        const int qr = qrow0 + li;
        if (qr < NSEQ){
            q0 = *(const bf16x8*)(Qg + (size_t)qr*ROWQ + lg*8);
            q1 = *(const bf16x8*)(Qg + (size_t)qr*ROWQ + 32 + lg*8);
        }
        // S^T tile: sf[nt2][r] = S[q=li][k = nt2*16 + lg*4 + r]
        f32x4 sf[16];
        #pragma unroll
        for (int nt2=0; nt2<16; nt2++){
            const bf16x8 kb0 = *(const bf16x8*)&Ks[nt2*16+li][lg*8];
            const bf16x8 kb1 = *(const bf16x8*)&Ks[nt2*16+li][32+lg*8];
            f32x4 s; s[0]=0.f; s[1]=0.f; s[2]=0.f; s[3]=0.f;
            s = __builtin_amdgcn_mfma_f32_16x16x32_bf16(kb0, q0, s, 0,0,0);
            s = __builtin_amdgcn_mfma_f32_16x16x32_bf16(kb1, q1, s, 0,0,0);
            sf[nt2] = s;
        }
        // mask k >= 243: nt2=15, k = 240 + lg*4 + r -> mask iff lg*4+r >= 3
        sf[15][3] = -1e30f;
        if (lg){ sf[15][0] = -1e30f; sf[15][1] = -1e30f; sf[15][2] = -1e30f; }
        // per-lane softmax over this lane's 64 scores (q = li)
        float m = sf[0][0];
        #pragma unroll
        for (int nt2=0; nt2<16; nt2++)
            #pragma unroll
            for (int r=0;r<4;r++) m = fmaxf(m, sf[nt2][r]);
        m = fmaxf(m, __shfl_xor(m,16));
        m = fmaxf(m, __shfl_xor(m,32));
        float sum = 0.f;
        #pragma unroll
        for (int nt2=0; nt2<16; nt2++)
            #pragma unroll
            for (int r=0;r<4;r++){
                const float pv = __expf(scale*(sf[nt2][r]-m));
                sf[nt2][r] = pv; sum += pv;
            }
        sum += __shfl_xor(sum,16);
        sum += __shfl_xor(sum,32);
        const float inv = 1.f/sum;
        // pack P (unnormalized) to bf16 pairs
        u32 ulo[16], uhi[16];
        #pragma unroll
        for (int nt2=0; nt2<16; nt2++){
            ulo[nt2] = (u32)f2bf(sf[nt2][0]) | ((u32)f2bf(sf[nt2][1]) << 16);
            uhi[nt2] = (u32)f2bf(sf[nt2][2]) | ((u32)f2bf(sf[nt2][3]) << 16);
        }
        // redistribute to PV A-fragments: pa[kt] elem e = P[q=li][k=kt*32+lg*8+e]
        bf16x8 pa[8];
        #pragma unroll
        for (int kt=0; kt<8; kt++){
            u32 a0 = __shfl((int)ulo[2*kt],   laneA), a1 = __shfl((int)ulo[2*kt+1], laneA);
            u32 b0 = __shfl((int)uhi[2*kt],   laneA), b1 = __shfl((int)uhi[2*kt+1], laneA);
            u32 c0 = __shfl((int)ulo[2*kt],   laneB), c1 = __shfl((int)ulo[2*kt+1], laneB);
            u32 d0 = __shfl((int)uhi[2*kt],   laneB), d1 = __shfl((int)uhi[2*kt+1], laneB);
            union { u32 u[4]; bf16x8 v; } pk;
            pk.u[0] = sel ? a1 : a0;
            pk.u[1] = sel ? b1 : b0;
            pk.u[2] = sel ? c1 : c0;
            pk.u[3] = sel ? d1 : d0;
            pa[kt] = pk.v;
        }
        // inv for output rows q_local = lg*4+r
        float invr[4];
        #pragma unroll
        for (int r=0;r<4;r++) invr[r] = __shfl(inv, lg*4+r);
        // O = P V  (O[q=lg*4+r][d=dn*16+li])
        #pragma unroll
        for (int dn=0;dn<4;dn++){
            f32x4 o; o[0]=0.f; o[1]=0.f; o[2]=0.f; o[3]=0.f;
            #pragma unroll
            for (int kt=0;kt<8;kt++){
                const bf16x8 vb = *(const bf16x8*)&Vs[dn*16+li][kt*32 + lg*8];
                o = __builtin_amdgcn_mfma_f32_16x16x32_bf16(pa[kt], vb, o, 0,0,0);
            }
            #pragma unroll
            for (int r=0;r<4;r++){
                const int qrow = qrow0 + lg*4 + r;
                if (qrow < NSEQ){
                    const size_t off = ((size_t)bj*243 + qrow)*512 + h*64 + dn*16 + li;
                    float val = o[r] * invr[r];
                    if (phase == 1) val += bf2f(attn[off]);
                    attn[off] = f2bf(val);
                }
            }
        }
    }
}

// ---------------- projection GEMM  M=33048 x N=512 x K=512 -> fp32 fuse ----------------
__global__ __launch_bounds__(256) void k_gemm_proj(
    const u16* __restrict__ attnb, const u16* __restrict__ WprojT,
    const float* __restrict__ b_proj, float* __restrict__ fuse)
{
    __shared__ __align__(16) u16 smem[8192];
    u16* As = smem;
    u16* Bs = smem + 4096;

    // bijective XCD swizzle over 1036 blocks (q=129, r=4)
    const int orig = blockIdx.x;
    const int xcd  = orig & 7;
    const int wg   = (xcd < 4 ? xcd*130 : 4*130 + (xcd-4)*129) + (orig >> 3);
    const int nt = wg & 3, mt = wg >> 2;

    const int tid = threadIdx.x;
    const int w = tid >> 6, lane = tid & 63;
    const int wm = w >> 1, wn = w & 1;
    const int lg = lane >> 4, li = lane & 15;

    const int srow = w*16 + (lane >> 2);
    const int scol = (lane & 3) * 8;
    const u16* gA0 = attnb  + (size_t)(mt*128 + srow)*512 + scol;
    const u16* gA1 = gA0 + (size_t)64*512;
    const u16* gB0 = WprojT + (size_t)(nt*128 + srow)*512 + scol;
    const u16* gB1 = gB0 + (size_t)64*512;
    u16* lA0 = As + w*512;           u16* lA1 = As + 2048 + w*512;
    u16* lB0 = Bs + w*512;           u16* lB1 = Bs + 2048 + w*512;

    f32x4 acc[4][4];
    #pragma unroll
    for (int i=0;i<4;i++)
        #pragma unroll
        for (int jj=0;jj<4;jj++){ acc[i][jj][0]=0.f; acc[i][jj][1]=0.f; acc[i][jj][2]=0.f; acc[i][jj][3]=0.f; }

    for (int k0 = 0; k0 < 512; k0 += 32){
        __syncthreads();
        gload_lds16(gA0 + k0, lA0);
        gload_lds16(gA1 + k0, lA1);
        gload_lds16(gB0 + k0, lB0);
        gload_lds16(gB1 + k0, lB1);
        __syncthreads();
        bf16x8 av[4], bv[4];
        #pragma unroll
        for (int mf=0;mf<4;mf++) av[mf] = *(const bf16x8*)&As[(wm*64 + mf*16 + li)*32 + lg*8];
        #pragma unroll
        for (int nf=0;nf<4;nf++) bv[nf] = *(const bf16x8*)&Bs[(wn*64 + nf*16 + li)*32 + lg*8];
        #pragma unroll
        for (int mf=0;mf<4;mf++)
            #pragma unroll
            for (int nf=0;nf<4;nf++)
                acc[mf][nf] = __builtin_amdgcn_mfma_f32_16x16x32_bf16(av[mf], bv[nf], acc[mf][nf], 0, 0, 0);
    }

    #pragma unroll
    for (int mf=0;mf<4;mf++)
        #pragma unroll
        for (int reg=0;reg<4;reg++){
            const int rr = mt*128 + wm*64 + mf*16 + lg*4 + reg;
            if (rr < TOK){
                #pragma unroll
                for (int nf=0;nf<4;nf++){
                    const int c = nt*128 + wn*64 + nf*16 + li;
                    fuse[(size_t)rr*512 + c] = acc[mf][nf][reg] + b_proj[c];
                }
            }
        }
}

// ---------------- residual + LayerNorm (with (b,j,n)->(b,n,j) permute) ----------------
__global__ __launch_bounds__(256) void k_ln(
    const float* __restrict__ x, const float* __restrict__ fuse, float* __restrict__ out)
{
    const int w = threadIdx.x >> 6, lane = threadIdx.x & 63;
    const int o = blockIdx.x*4 + w;     // row in (b,n,j) order, exact 33048
    const unsigned b_  = (unsigned)o / 4131u;
    const unsigned rem = (unsigned)o % 4131u;
    const unsigned n = rem / 17u, j = rem % 17u;
    const unsigned t = (b_*17u + j)*243u + n;
    const float* fr = fuse + (size_t)t*512 + lane*8;
    const float* xr = x    + (size_t)o*512 + lane*8;
    f32x4 f0 = *(const f32x4*)fr, f1 = *(const f32x4*)(fr+4);
    f32x4 x0 = *(const f32x4*)xr, x1 = *(const f32x4*)(xr+4);
    float y[8];
    #pragma unroll
    for (int e=0;e<4;e++){ y[e] = x0[e]+f0[e]; y[e+4] = x1[e]+f1[e]; }
    float s1=0.f, s2=0.f;
    #pragma unroll
    for (int e=0;e<8;e++){ s1 += y[e]; s2 += y[e]*y[e]; }
    #pragma unroll
    for (int m=1;m<64;m<<=1){ s1 += __shfl_xor(s1,m); s2 += __shfl_xor(s2,m); }
    const float mu  = s1 * (1.f/512.f);
    const float var = s2 * (1.f/512.f) - mu*mu;
    const float rstd = rsqrtf(var + 1e-5f);
    float* orow = out + (size_t)o*512 + lane*8;
    f32x4 o0, o1;
    #pragma unroll
    for (int e=0;e<4;e++){ o0[e] = (y[e]-mu)*rstd; o1[e] = (y[e+4]-mu)*rstd; }
    *(f32x4*)orow = o0; *(f32x4*)(orow+4) = o1;
}

extern "C" void kernel_launch(void* const* d_in, const int* in_sizes, int n_in,
                              void* d_out, int out_size, void* d_ws, size_t ws_size,
                              hipStream_t stream)
{
    const float* x      = (const float*)d_in[0];
    const float* W_qkv  = (const float*)d_in[1];
    const float* b_qkv  = (const float*)d_in[2];
    const float* W_q    = (const float*)d_in[3];
    const float* b_q    = (const float*)d_in[4];
    const float* W_kv   = (const float*)d_in[5];
    const float* b_kv   = (const float*)d_in[6];
    const float* W_proj = (const float*)d_in[7];
    const float* b_proj = (const float*)d_in[8];

    // workspace layout (peak ~173.1 MB):
    //   [0, 33972224)            xbf  bf16 [33048+pad][512]
    //   [33972224, 135495680)    ws3  bf16 [33048][1536]
    //   [135495680, 169467904)   attn bf16 [33048+pad][512]
    //   [169467904, 172613632)   WcatT bf16 [3072][512]
    //   [172613632, 173137920)   WprojT bf16 [512][512]
    //   fuse fp32 aliases ws3 (dead after attn phase 1)
    char* ws = (char*)d_ws;
    u16*   xbf    = (u16*)(ws);
    u16*   ws3    = (u16*)(ws + 33972224u);
    u16*   attn   = (u16*)(ws + 135495680u);
    u16*   WcatT  = (u16*)(ws + 169467904u);
    u16*   WprojT = (u16*)(ws + 172613632u);
    float* fuse   = (float*)(ws + 33972224u);
    float* out    = (float*)d_out;

    k_cvt_xbf  <<<8262, 256, 0, stream>>>(x, xbf);
    k_cvt_wcat <<<768,  256, 0, stream>>>(W_qkv, W_q, W_kv, WcatT);
    k_cvt_wproj<<<128,  256, 0, stream>>>(W_proj, WprojT);

    k_gemm_in<<<3108, 256, 0, stream>>>(xbf, WcatT, b_qkv, b_q, b_kv, ws3, 0);
    k_attn<<<1088, 256, 0, stream>>>(ws3, attn, 0);

    k_gemm_in<<<3108, 256, 0, stream>>>(xbf, WcatT, b_qkv, b_q, b_kv, ws3, 1536);
    k_attn<<<1088, 256, 0, stream>>>(ws3, attn, 1);

    k_gemm_proj<<<1036, 256, 0, stream>>>(attn, WprojT, b_proj, fuse);

    k_ln<<<8262, 256, 0, stream>>>(x, fuse, out);
}